// Round 5
// baseline (49.386 us; speedup 1.0000x reference)
//
#include <hip/hip_runtime.h>

// LIF neuron scan: x [64, 1024, 512] f32 -> spikes [64, 1024, 512] f32 (0/1)
// m = 0.95*m + x[t]; s = (m > 0.5); m = s ? 0 : m
// 32768 independent chains -> 512 single-wave blocks (2/CU). Parallelism is
// structurally capped, so the memory pipe must be fed by ILP. Round-3 showed
// the compiler only sustains ~40 outstanding dword loads/wave (~20KB/CU in
// flight) vs the ~22KB/CU latency-BW product -> read-MLP bound.
//
// This version quadruples bytes-per-vmcnt-slot:
//  - x staged to LDS with global_load_lds dwordx4 (1KB/wave-instr, 16/chunk),
//    double-buffered, hand-counted s_waitcnt vmcnt(16/32) so the next chunk's
//    16KB/wave stays in flight through the whole compute phase (m218 pattern:
//    never drain to 0 in the loop).
//  - spikes transposed through LDS and written as 16 nt dwordx4 stores/chunk
//    (4x fewer store slots in the in-order vmcnt queue).
// LDS mapping for global_load_lds is linear base+lane*16 (m104 constraint):
// instr i, lane l -> t_local = 4i + (l>>4), f = 4*(l&15); matches [t][f] layout.
// Compute-phase LDS ops are lane==f -> 2-way bank aliasing (free, m136).
// Non-fused mul/add (np ref rounds separately; 0/1 threshold makes ulp
// differences avalanche down the chain).

#define BATCH 64
#define SEQ   1024
#define FEAT  512
#define CHUNK 64
#define NCHUNK (SEQ / CHUNK)   // 16
#define LPC 16                 // load/store instrs per chunk (CHUNK*64*4B / 1KB)

typedef const __attribute__((address_space(1))) void gas_void;
typedef __attribute__((address_space(3))) void las_void;
typedef float f32x4 __attribute__((ext_vector_type(4)));   // native clang vector
                                                           // (HIP float4 is a class
                                                           // nontemporal builtin rejects)

__global__ __launch_bounds__(64, 1)
void lif_kernel(const float* __restrict__ x, float* __restrict__ out) {
    __shared__ float lds_x[2][CHUNK * 64];   // [t_local][f_local], 16 KB each
    __shared__ float lds_s[CHUNK * 64];      // spike transpose buffer, 16 KB

    const int bid  = blockIdx.x;
    const int b    = bid >> 3;            // batch row
    const int f0   = (bid & 7) << 6;      // 64-feature group
    const int lane = threadIdx.x;         // one wave per block

    const int t_sub = lane >> 4;          // 0..3   (t within a 4-step group)
    const int fw    = (lane & 15) << 2;   // 0..60  (float offset within row seg)

    const float* __restrict__ xp = x   + (size_t)b * SEQ * FEAT + f0;
    float* __restrict__       op = out + (size_t)b * SEQ * FEAT + f0;

    // stage CHUNK time-steps of this block's 64-feature slab into lds_x[buf]
#define STAGE(bufidx, t0)                                                     \
    {                                                                         \
        _Pragma("unroll")                                                     \
        for (int i = 0; i < LPC; ++i) {                                       \
            const float* src = xp + (size_t)((t0) + 4 * i + t_sub) * FEAT + fw; \
            __builtin_amdgcn_global_load_lds(                                 \
                (gas_void*)src, (las_void*)&lds_x[bufidx][i * 256], 16, 0, 0); \
        }                                                                     \
    }

    float m = 0.0f;

    STAGE(0, 0)                                   // prologue: chunk 0 in flight

    for (int k = 0; k < NCHUNK; ++k) {
        const int buf = k & 1;
        if (k + 1 < NCHUNK) STAGE(buf ^ 1, (k + 1) * CHUNK)   // prefetch next

        // ensure chunk k's 16 loads retired WITHOUT draining the prefetch.
        // ops issued after chunk-k's loads: k==0: L1(16); steady: S_{k-1}(16)
        // + L_{k+1}(16) = 32; k==NCHUNK-1: S_{k-1}(16) only.
        if (k == 0 || k == NCHUNK - 1)
            asm volatile("s_waitcnt vmcnt(16)" ::: "memory");
        else
            asm volatile("s_waitcnt vmcnt(32)" ::: "memory");
        __builtin_amdgcn_sched_barrier(0);

        // sequential LIF over this chunk; lane owns feature f0+lane
#pragma unroll
        for (int t = 0; t < CHUNK; ++t) {
            const float xv = lds_x[buf][t * 64 + lane];
            m = __fadd_rn(__fmul_rn(0.95f, m), xv);
            const bool fired = (m > 0.5f);
            lds_s[t * 64 + lane] = fired ? 1.0f : 0.0f;
            m = fired ? 0.0f : m;
        }

        // spike writes must land before the transposed b128 reads
        asm volatile("s_waitcnt lgkmcnt(0)" ::: "memory");
        __builtin_amdgcn_sched_barrier(0);

        // transposed cooperative stores: 16 x nt dwordx4 (1KB/wave-instr)
        const int t0 = k * CHUNK;
#pragma unroll
        for (int i = 0; i < LPC; ++i) {
            const f32x4 v =
                *reinterpret_cast<const f32x4*>(&lds_s[i * 256 + 4 * lane]);
            __builtin_nontemporal_store(
                v, reinterpret_cast<f32x4*>(op + (size_t)(t0 + 4 * i + t_sub) * FEAT + fw));
        }
    }
#undef STAGE
}

extern "C" void kernel_launch(void* const* d_in, const int* in_sizes, int n_in,
                              void* d_out, int out_size, void* d_ws, size_t ws_size,
                              hipStream_t stream) {
    const float* x = (const float*)d_in[0];
    float* out = (float*)d_out;
    const int grid = BATCH * 8;   // 512 single-wave blocks
    lif_kernel<<<grid, 64, 0, stream>>>(x, out);
}